// Round 7
// baseline (120.807 us; speedup 1.0000x reference)
//
#include <hip/hip_runtime.h>
#include <math.h>

#define LAYERS  8
#define FEAT    3072
#define NCLASS  10
#define DIM     4096

typedef float v2f __attribute__((ext_vector_type(2)));
typedef float v4f __attribute__((ext_vector_type(4)));
typedef unsigned u32x2 __attribute__((ext_vector_type(2)));

// prefix-xor (inverse Gray) of 6-bit value; compile-time under unroll
__device__ __forceinline__ int px6c(int r) {
    int u = r ^ (r >> 1); u ^= u >> 2; u ^= u >> 4; return u & 63;
}
__device__ __forceinline__ int gray6(int r) { return (r ^ (r >> 1)) & 63; }

__device__ __forceinline__ float getc(const v2f v[32], int u) {
    return (u & 1) ? v[u >> 1].y : v[u >> 1].x;
}
__device__ __forceinline__ void setc(v2f v[32], int u, float x) {
    if (u & 1) v[u >> 1].y = x; else v[u >> 1].x = x;
}
__device__ __forceinline__ float bpermf(int addr, float x) {
    return __int_as_float(__builtin_amdgcn_ds_bpermute(addr, __float_as_int(x)));
}

// ---- FIXED B-LAYOUT kernel (R7): v[r] = psi[64r + t] forever. No transposes.
//      Reg qubits 5..0 -> shear butterflies on v[] index bits (verified R4 code).
//      Lane qubits 6..11 -> cross-lane butterflies on lane-bit k (t^2^k):
//        k=0,1: DPP quad_perm (VALU)     k=4,5: permlane16/32_swap (VALU, pair trick)
//        k=2,3: ds_swizzle XOR (DS crossbar, independent ops, no serialization)
//      sigma-form: new[p] = own + (bit_k(own) ? +t : -t) * partner.
//      Layer perm = verbatim verified GrayB (complete 12-bit Gray in B layout).

// reg-qubit shear butterflies (stages p=0..5 use tl[off-p]) -- verified R4
__device__ __forceinline__ void butterflies6t(v2f v[32],
                                              const float* __restrict__ tl,
                                              int off) {
    {
        const float tt = tl[off];
#pragma unroll
        for (int i = 0; i < 32; ++i) {
            v2f a = v[i];
            v[i].x = fmaf(-tt, a.y, a.x);
            v[i].y = fmaf( tt, a.x, a.y);
        }
    }
#pragma unroll
    for (int p = 1; p < 6; ++p) {
        const float tt = tl[off - p];
#pragma unroll
        for (int i0 = 0; i0 < 32; ++i0) {
            if (i0 & (1 << (p - 1))) continue;
            const int i1 = i0 | (1 << (p - 1));
            v2f a = v[i0], e = v[i1];
            v[i0].x = fmaf(-tt, e.x, a.x);
            v[i0].y = fmaf(-tt, e.y, a.y);
            v[i1].x = fmaf( tt, a.x, e.x);
            v[i1].y = fmaf( tt, a.y, e.y);
        }
    }
}

// lane stage via DPP (lane^1: CTRL=0xB1, lane^2: CTRL=0x4E); ts = per-lane +/-t
template<int CTRL>
__device__ __forceinline__ void laneStageDpp(v2f v[32], float ts) {
#pragma unroll
    for (int i = 0; i < 32; ++i) {
        float ax = __int_as_float(__builtin_amdgcn_update_dpp(
            0, __float_as_int(v[i].x), CTRL, 0xF, 0xF, true));
        float ay = __int_as_float(__builtin_amdgcn_update_dpp(
            0, __float_as_int(v[i].y), CTRL, 0xF, 0xF, true));
        v[i].x = fmaf(ts, ax, v[i].x);
        v[i].y = fmaf(ts, ay, v[i].y);
    }
}

// lane stage via ds_swizzle XOR (lane^4: 0x101F, lane^8: 0x201F); ts = +/-t
template<int IMM>
__device__ __forceinline__ void laneStageSwz(v2f v[32], float ts) {
#pragma unroll
    for (int i = 0; i < 32; ++i) {
        float ax = __int_as_float(__builtin_amdgcn_ds_swizzle(__float_as_int(v[i].x), IMM));
        float ay = __int_as_float(__builtin_amdgcn_ds_swizzle(__float_as_int(v[i].y), IMM));
        v[i].x = fmaf(ts, ax, v[i].x);
        v[i].y = fmaf(ts, ay, v[i].y);
    }
}

// lane^32 via permlane32_swap pair trick: after swap, r.x = all bit5=0 elems,
// r.y = all bit5=1 elems, lanewise-paired -> uniform-sign FMAs, swap back.
__device__ __forceinline__ void laneStagePl32(v2f v[32], float tt) {
#pragma unroll
    for (int i = 0; i < 32; ++i) {
        u32x2 r = __builtin_amdgcn_permlane32_swap(
            __float_as_int(v[i].x), __float_as_int(v[i].y), false, false);
        float lo = __int_as_float(r.x), hi = __int_as_float(r.y);
        float nlo = fmaf(-tt, hi, lo);
        float nhi = fmaf( tt, lo, hi);
        u32x2 r2 = __builtin_amdgcn_permlane32_swap(
            __float_as_int(nlo), __float_as_int(nhi), false, false);
        v[i].x = __int_as_float(r2.x);
        v[i].y = __int_as_float(r2.y);
    }
}

#if __has_builtin(__builtin_amdgcn_permlane16_swap)
#define HAVE_PL16 1
// lane^16 via permlane16_swap pair trick (16-lane rows; same algebra as pl32)
__device__ __forceinline__ void laneStagePl16(v2f v[32], float tt) {
#pragma unroll
    for (int i = 0; i < 32; ++i) {
        u32x2 r = __builtin_amdgcn_permlane16_swap(
            __float_as_int(v[i].x), __float_as_int(v[i].y), false, false);
        float lo = __int_as_float(r.x), hi = __int_as_float(r.y);
        float nlo = fmaf(-tt, hi, lo);
        float nhi = fmaf( tt, lo, hi);
        u32x2 r2 = __builtin_amdgcn_permlane16_swap(
            __float_as_int(nlo), __float_as_int(nhi), false, false);
        v[i].x = __int_as_float(r2.x);
        v[i].y = __int_as_float(r2.y);
    }
}
#else
#define HAVE_PL16 0
#endif

__global__ __launch_bounds__(64)
void qnn_kernel(const float* __restrict__ x,
                const float* __restrict__ ang,
                const float* __restrict__ W,
                const float* __restrict__ bias,
                float* __restrict__ out)
{
    __shared__ __attribute__((aligned(16))) float lds[DIM];   // epilogue only (16 KB)
    __shared__ float tnt[96];

    const int t = threadIdx.x;          // 0..63, single wave per block/state
    const int b = blockIdx.x;

    // ---- tangent table (96 angles) + product of all 96 cosines ----
    float cprod2;
    {
        float a0 = ang[t];
        float c0 = cosf(a0), s0 = sinf(a0);
        tnt[t] = s0 / c0;
        float pc = c0;
        if (t < 32) {
            float a1 = ang[64 + t];
            float c1 = cosf(a1), s1 = sinf(a1);
            tnt[64 + t] = s1 / c1;
            pc *= c1;
        }
#pragma unroll
        for (int o = 1; o < 64; o <<= 1) pc *= __shfl_xor(pc, o, 64);
        cprod2 = pc * pc;               // (prod cos)^2, uniform across wave
    }

    // ---- load psi0 in B layout: v[r] = psi[64r + t] (coalesced b32) ----
    v2f v[32];
    {
        const float* xb = x + (size_t)b * FEAT;
#pragma unroll
        for (int r = 0; r < 64; ++r) {
            if (r < FEAT / 64) setc(v, r, xb[64 * r + t]);
            else               setc(v, r, 0.f);
        }
    }

    // ---- ||x||^2 (normalization deferred: circuit is linear); fold C^2 in ----
    float invn2;
    {
        v2f s2 = {0.f, 0.f};
#pragma unroll
        for (int i = 0; i < 32; ++i) s2 += v[i] * v[i];
        float ss = s2.x + s2.y;
#pragma unroll
        for (int o = 1; o < 64; o <<= 1) ss += __shfl_xor(ss, o, 64);
        invn2 = cprod2 / ss;
    }

    // ---- anti-lock-step skew keyed on the HW wave slot ----
    {
        const int slot = __builtin_amdgcn_s_getreg(4 | (0 << 6) | (3 << 11)) & 7;
#pragma unroll 1
        for (int i = 0; i < slot; ++i) __builtin_amdgcn_s_sleep(12);   // 12*64 cyc
    }

    // ---- per-lane constants ----
    int px = t ^ (t >> 1); px ^= px >> 2; px ^= px >> 4; px &= 63;  // px6(t)
    const int A0 = 4 * px;                    // GrayB bpermute byte addrs
    const int A1 = 4 * (px ^ 63);
    const int gtl = gray6(t);
    // sign masks: sigma = +1 iff own lane-bit k == 1 (sign-bit XOR on tangent)
    const int NEGBIT = (int)0x80000000u;
    const int sm0 = (t & 1)  ? 0 : NEGBIT;
    const int sm1 = (t & 2)  ? 0 : NEGBIT;
    const int sm2 = (t & 4)  ? 0 : NEGBIT;
    const int sm3 = (t & 8)  ? 0 : NEGBIT;
#if !HAVE_PL16
    const int sm4 = (t & 16) ? 0 : NEGBIT;
    const int a16 = 4 * (t ^ 16);             // bpermute fallback addr for ^16
#endif

#pragma unroll 1
    for (int p = 0; p < LAYERS; ++p) {
        float tb[12];
#pragma unroll
        for (int q = 0; q < 12; ++q) tb[q] = tnt[12 * p + q];

        // ---- Ry on all 12 qubits, fixed layout (stages commute; DS spread out) ----
        // lane-bit k rotates qubit 11-k with tangent tb[11-k]
        laneStageSwz<0x101F>(v, __int_as_float(__float_as_int(tb[9]) ^ sm2));   // ^4
        laneStageDpp<0xB1>  (v, __int_as_float(__float_as_int(tb[11]) ^ sm0));  // ^1
        laneStageSwz<0x201F>(v, __int_as_float(__float_as_int(tb[8]) ^ sm3));   // ^8
        laneStageDpp<0x4E>  (v, __int_as_float(__float_as_int(tb[10]) ^ sm1));  // ^2
#if HAVE_PL16
        laneStagePl16(v, tb[7]);                                                // ^16
#else
        {   // bpermute fallback for ^16
            const float ts = __int_as_float(__float_as_int(tb[7]) ^ sm4);
#pragma unroll
            for (int i = 0; i < 32; ++i) {
                float ax = bpermf(a16, v[i].x);
                float ay = bpermf(a16, v[i].y);
                v[i].x = fmaf(ts, ax, v[i].x);
                v[i].y = fmaf(ts, ay, v[i].y);
            }
        }
#endif
        laneStagePl32(v, tb[6]);                                                // ^32
        // reg qubits 5..0 (verified shear butterflies)
        butterflies6t(v, tb, 5);

        // ---- layer CNOT chain == full 12-bit Gray in B layout (verified GrayB);
        //      layer 7's Gray folds into the epilogue scatter ----
        if (p < LAYERS - 1) {
            float n[64];
#pragma unroll
            for (int r = 0; r < 64; ++r) {
                const int srcr = px6c(r);                 // compile-time
                n[r] = bpermf((srcr & 1) ? A1 : A0, getc(v, srcr));
            }
#pragma unroll
            for (int r = 0; r < 64; ++r)
                setc(v, r, n[r]);
        }
    }

    // ---- epilogue (B layout, Gray(7) folded): q[g(j)] = psi[j]^2,
    //      j = 64r + t, g(j) = 64*gray6(r) + (gray6(t) ^ 32*(r&1)) ----
#pragma unroll
    for (int i = 0; i < 32; ++i) {
        const int g0 = 64 * gray6(2 * i);
        const int g1 = 64 * (gray6(2 * i) ^ 1);
        lds[g0 + gtl]        = v[i].x * v[i].x;   // bank = gtl&31: 2-way, free
        lds[g1 + (gtl ^ 32)] = v[i].y * v[i].y;
    }

    float acc[NCLASS];
#pragma unroll
    for (int c = 0; c < NCLASS; ++c) acc[c] = 0.f;

#pragma unroll 1
    for (int k = 0; k < 16; ++k) {
        const v4f q4 = *(const v4f*)(lds + 4 * t + 256 * k);   // b128, floor-free
        const float* wp = W + 4 * t + 256 * k;
#pragma unroll
        for (int c = 0; c < NCLASS; ++c) {
            const v4f w4 = *(const v4f*)(wp + c * DIM);         // dwordx4, L2-resident
            acc[c] += q4.x * w4.x + q4.y * w4.y + q4.z * w4.z + q4.w * w4.w;
        }
    }

#pragma unroll
    for (int c = 0; c < NCLASS; ++c) {
        float a = acc[c];
#pragma unroll
        for (int o = 1; o < 64; o <<= 1) a += __shfl_xor(a, o, 64);
        if (t == 0) out[b * NCLASS + c] = fmaf(a, invn2, bias[c]);
    }
}

extern "C" void kernel_launch(void* const* d_in, const int* in_sizes, int n_in,
                              void* d_out, int out_size, void* d_ws, size_t ws_size,
                              hipStream_t stream) {
    const float* x    = (const float*)d_in[0];
    const float* ang  = (const float*)d_in[1];
    const float* W    = (const float*)d_in[2];
    const float* bias = (const float*)d_in[3];
    float* out = (float*)d_out;
    const int batch = in_sizes[0] / FEAT;   // 2048
    qnn_kernel<<<batch, 64, 0, stream>>>(x, ang, W, bias, out);
}

// Round 9
// 105.560 us; speedup vs baseline: 1.1444x; 1.1444x over previous
//
#include <hip/hip_runtime.h>
#include <math.h>

#define LAYERS  8
#define FEAT    3072
#define NCLASS  10
#define DIM     4096
#define ST      68   // padded LDS row stride (floats); ST%4==0 -> b128-able, ST%32==4

typedef float v2f __attribute__((ext_vector_type(2)));
typedef float v4f __attribute__((ext_vector_type(4)));

// prefix-xor (inverse Gray) of 6-bit value; compile-time under unroll
__device__ __forceinline__ int px6c(int r) {
    int u = r ^ (r >> 1); u ^= u >> 2; u ^= u >> 4; return u & 63;
}
__device__ __forceinline__ int gray6(int r) { return (r ^ (r >> 1)) & 63; }

__device__ __forceinline__ float getc(const v2f v[32], int u) {
    return (u & 1) ? v[u >> 1].y : v[u >> 1].x;
}
__device__ __forceinline__ void setc(v2f v[32], int u, float x) {
    if (u & 1) v[u >> 1].y = x; else v[u >> 1].x = x;
}
__device__ __forceinline__ float bpermf(int addr, float x) {
    return __int_as_float(__builtin_amdgcn_ds_bpermute(addr, __float_as_int(x)));
}

// ---- SHEAR butterflies (verified R4/R6): Ry(th) = cos(th)*[[1,-t],[t,1]].
//      cos factors commute out; C^2 folded into invn2. 2 FMA per pair.
//      R8 lesson: GrayB CANNOT be folded register-locally into the even
//      B-phase (px12 masks of element bits 6..11 span all lane bits) --
//      the eager bpermute GrayB below is the verified form; keep it.

// plain global stage on element-bit B (B>=2): reg pairs (i, i|(1<<(B-1)))
__device__ __forceinline__ void stageP(v2f v[32], int B, float tt) {
#pragma unroll
    for (int i0 = 0; i0 < 32; ++i0) {
        if (i0 & (1 << (B - 1))) continue;
        const int i1 = i0 | (1 << (B - 1));
        v2f a = v[i0], e = v[i1];
        v[i0].x = fmaf(-tt, e.x, a.x);
        v[i0].y = fmaf(-tt, e.y, a.y);
        v[i1].x = fmaf( tt, a.x, e.x);
        v[i1].y = fmaf( tt, a.y, e.y);
    }
}

// renamed global stage b (2..4): pairs (m, m^((1<<b)-1)), swapped partner (GrayA-conj)
__device__ __forceinline__ void stageRb(v2f v[32], int b, float tt) {
#pragma unroll
    for (int m = 0; m < 32; ++m) {
        if (m & (1 << (b - 1))) continue;
        const int part = m ^ ((1 << b) - 1);
        const float tg = (m & (1 << b)) ? -tt : tt;
        v2f A = v[m], E = v[part];
        v[m].x    = fmaf(-tg, E.y, A.x);
        v[m].y    = fmaf(-tg, E.x, A.y);
        v[part].x = fmaf( tg, A.y, E.x);
        v[part].y = fmaf( tg, A.x, E.y);
    }
}
// renamed b=5: pairs (m, m^31), tt = psgn*tl[6]
__device__ __forceinline__ void stageR5(v2f v[32], float tt) {
#pragma unroll
    for (int m = 0; m < 16; ++m) {
        const int part = m ^ 31;
        v2f A = v[m], E = v[part];
        v[m].x    = fmaf(-tt, E.y, A.x);
        v[m].y    = fmaf(-tt, E.x, A.y);
        v[part].x = fmaf( tt, A.y, E.x);
        v[part].y = fmaf( tt, A.x, E.y);
    }
}

__global__ __launch_bounds__(64)
void qnn_kernel(const float* __restrict__ x,
                const float* __restrict__ ang,
                const float* __restrict__ W,
                const float* __restrict__ bias,
                float* __restrict__ out)
{
    __shared__ __attribute__((aligned(16))) float lds[ST * 64];  // 17408 B
    __shared__ float tnt[96];

    const int t = threadIdx.x;          // 0..63, single wave per block/state
    const int b = blockIdx.x;

    // ---- tangent table (96 angles) + product of all 96 cosines ----
    float cprod2;
    {
        float a0 = ang[t];
        float c0 = cosf(a0), s0 = sinf(a0);
        tnt[t] = s0 / c0;
        float pc = c0;
        if (t < 32) {
            float a1 = ang[64 + t];
            float c1 = cosf(a1), s1 = sinf(a1);
            tnt[64 + t] = s1 / c1;
            pc *= c1;
        }
#pragma unroll
        for (int o = 1; o < 64; o <<= 1) pc *= __shfl_xor(pc, o, 64);
        cprod2 = pc * pc;               // (prod cos)^2, uniform across wave
    }

    // ---- load psi0 directly in B layout: v[r] = psi[64r + t] (coalesced b32) ----
    v2f v[32];
    {
        const float* xb = x + (size_t)b * FEAT;
#pragma unroll
        for (int r = 0; r < 64; ++r) {
            if (r < FEAT / 64) setc(v, r, xb[64 * r + t]);
            else               setc(v, r, 0.f);
        }
    }

    // ---- ||x||^2 (normalization deferred: circuit is linear); fold C^2 in ----
    float invn2;
    {
        v2f s2 = {0.f, 0.f};
#pragma unroll
        for (int i = 0; i < 32; ++i) s2 += v[i] * v[i];
        float ss = s2.x + s2.y;
#pragma unroll
        for (int o = 1; o < 64; o <<= 1) ss += __shfl_xor(ss, o, 64);
        invn2 = cprod2 / ss;
    }

    // ---- anti-lock-step skew keyed on the HW wave slot. R9: quantum doubled
    //      (slot*1536 cyc, spread ~10.7k ~= 3/4 layer period) to desync the
    //      per-CU DS bursts; R6's slot*768 spread only ~1/3 of a period. ----
    {
        const int slot = __builtin_amdgcn_s_getreg(4 | (0 << 6) | (3 << 11)) & 7;
#pragma unroll 1
        for (int i = 0; i < slot; ++i) __builtin_amdgcn_s_sleep(24);   // 24*64 cyc
    }

    // ---- per-lane constants ----
    int px = t ^ (t >> 1); px ^= px >> 2; px ^= px >> 4; px &= 63;  // px6(t)
    const int A0 = 4 * px;                    // bpermute byte addrs (GrayB)
    const int A1 = 4 * (px ^ 63);
    const int u0 = t & 1;
    const float psgn = u0 ? -1.f : 1.f;       // parity sign for renamed b=5
    const int gtl = gray6(t);
    const int bp  = gtl + 32 * ST * u0;       // folded-GrayA store bases
    const int bm  = gtl - 32 * ST * u0;

    // ---- fused quad helpers (quad q = elements 4q..4q+3 = v[2q],v[2q+1]) ----

    // even/B-tail: bit0(t0) then bit1(t1) on quad, store b128 row chunk
    auto quadStoreB = [&](int q, float t1, float t0) {
        v2f a = v[2 * q], e = v[2 * q + 1];
        float b0 = fmaf(-t0, a.y, a.x), b1 = fmaf(t0, a.x, a.y);
        float b2 = fmaf(-t0, e.y, e.x), b3 = fmaf(t0, e.x, e.y);
        v4f qv = { fmaf(-t1, b2, b0), fmaf(-t1, b3, b1),
                   fmaf( t1, b0, b2), fmaf( t1, b1, b3) };
        *(v4f*)(lds + ST * t + 4 * q) = qv;
    };
    // A-head: 4 col reads -> bit0(t0) then bit1(t1)
    auto quadReadA = [&](int k, float t0, float t1) {
        const float a0 = lds[t + ST * (4 * k)];
        const float a1 = lds[t + ST * (4 * k + 1)];
        const float a2 = lds[t + ST * (4 * k + 2)];
        const float a3 = lds[t + ST * (4 * k + 3)];
        float b0 = fmaf(-t0, a1, a0), b1 = fmaf(t0, a0, a1);
        float b2 = fmaf(-t0, a3, a2), b3 = fmaf(t0, a2, a3);
        v[2 * k]     = (v2f){ fmaf(-t1, b2, b0), fmaf(-t1, b3, b1) };
        v[2 * k + 1] = (v2f){ fmaf( t1, b0, b2), fmaf( t1, b1, b3) };
    };
    // renamed tail: b=1(t10) then b=0(t11) on quad, folded-GrayA scatter
    auto quadStoreR = [&](int q, float t10, float t11) {
        v2f A = v[2 * q], E = v[2 * q + 1];
        const float tg = (q & 1) ? -t10 : t10;
        float nAx = fmaf(-tg, E.y, A.x), nAy = fmaf(-tg, E.x, A.y);
        float nEx = fmaf( tg, A.y, E.x), nEy = fmaf( tg, A.x, E.y);
        float r0 = fmaf(-t11, nAy, nAx);   // elem 4q   (even reg: te=+t11)
        float r1 = fmaf( t11, nAx, nAy);
        float r2 = fmaf( t11, nEy, nEx);   // elem 4q+2 (odd reg: te=-t11)
        float r3 = fmaf(-t11, nEx, nEy);
        const int g0 = gray6(4 * q);                 // compile-time
        const int base = ((g0 & 32) ? bm : bp);
        lds[base + ST * g0]       = r0;              // rows g0, g0^1, g0^3, g0^2
        lds[base + ST * (g0 ^ 1)] = r1;              // 2-way bank, free
        lds[base + ST * (g0 ^ 3)] = r2;
        lds[base + ST * (g0 ^ 2)] = r3;
    };
    // B-head: b128 row read -> bit0(t0) then bit1(t1)
    auto quadReadB = [&](int i, float t0, float t1) {
        v4f q4 = *(const v4f*)(lds + ST * t + 4 * i);
        float b0 = fmaf(-t0, q4.y, q4.x), b1 = fmaf(t0, q4.x, q4.y);
        float b2 = fmaf(-t0, q4.w, q4.z), b3 = fmaf(t0, q4.z, q4.w);
        v[2 * i]     = (v2f){ fmaf(-t1, b2, b0), fmaf(-t1, b3, b1) };
        v[2 * i + 1] = (v2f){ fmaf( t1, b0, b2), fmaf( t1, b1, b3) };
    };

    // ---- layer 0 (even, clean): B-phase, transpose B->A, A-phase ----
    {
        float tb[12];
#pragma unroll
        for (int q = 0; q < 12; ++q) tb[q] = tnt[q];
        // B-phase global bits 5..2 (tl[0..3]), then quad-fused bits 1,0 + store
        stageP(v, 5, tb[0]); stageP(v, 4, tb[1]);
        stageP(v, 3, tb[2]); stageP(v, 2, tb[3]);
#pragma unroll
        for (int q = 0; q < 16; ++q) quadStoreB(q, tb[4], tb[5]);
        // A-phase: quad-fused reads + bits 0,1 (tl[11],tl[10]), then global 2..5
#pragma unroll
        for (int k = 0; k < 16; ++k) quadReadA(k, tb[11], tb[10]);
        stageP(v, 2, tb[9]); stageP(v, 3, tb[8]);
        stageP(v, 4, tb[7]); stageP(v, 5, tb[6]);
        // GrayA(0): deferred into layer 1
    }

#pragma unroll 1
    for (int p = 0; p < 4; ++p) {
        // ======== odd layer 2p+1: renamed A-phase, folded transpose, B-phase ========
        {
            float tb[12];
#pragma unroll
            for (int q = 0; q < 12; ++q) tb[q] = tnt[(2 * p + 1) * 12 + q];

            // renamed global b=5,4,3,2 then quad-fused b=1,0 + GrayA scatter
            stageR5(v, psgn * tb[6]);
            stageRb(v, 4, tb[7]); stageRb(v, 3, tb[8]); stageRb(v, 2, tb[9]);
#pragma unroll
            for (int q = 0; q < 16; ++q) quadStoreR(q, tb[10], tb[11]);
            // B-phase: quad-fused row reads + bits 0,1 (tl[5],tl[4]), global 2..5
#pragma unroll
            for (int i = 0; i < 16; ++i) quadReadB(i, tb[5], tb[4]);
            stageP(v, 2, tb[3]); stageP(v, 3, tb[2]);
            stageP(v, 4, tb[1]); stageP(v, 5, tb[0]);

            if (p < 3) {
                // GrayB (eager): new[r] = bperm(parity(src)?A1:A0, old[px6(r)])
                float n[64];
#pragma unroll
                for (int r = 0; r < 64; ++r) {
                    const int srcr = px6c(r);         // compile-time
                    n[r] = bpermf((srcr & 1) ? A1 : A0, getc(v, srcr));
                }
#pragma unroll
                for (int r = 0; r < 64; ++r)
                    setc(v, r, n[r]);
            }
            // p == 3 (layer 7): final Gray folds into the epilogue scatter
        }

        if (p == 3) break;

        // ======== even layer 2p+2 (clean): B-phase, transpose B->A, A-phase ========
        {
            float tb[12];
#pragma unroll
            for (int q = 0; q < 12; ++q) tb[q] = tnt[(2 * p + 2) * 12 + q];

            stageP(v, 5, tb[0]); stageP(v, 4, tb[1]);
            stageP(v, 3, tb[2]); stageP(v, 2, tb[3]);
#pragma unroll
            for (int q = 0; q < 16; ++q) quadStoreB(q, tb[4], tb[5]);
#pragma unroll
            for (int k = 0; k < 16; ++k) quadReadA(k, tb[11], tb[10]);
            stageP(v, 2, tb[9]); stageP(v, 3, tb[8]);
            stageP(v, 4, tb[7]); stageP(v, 5, tb[6]);
            // GrayA: deferred into next odd layer
        }
    }

    // ---- epilogue (B layout, Gray(7) folded): q[g(j)] = psi[j]^2,
    //      j = 64r + t, g(j) = 64*gray6(r) + (gray6(t) ^ 32*(r&1)) ----
#pragma unroll
    for (int i = 0; i < 32; ++i) {
        const int g0 = 64 * gray6(2 * i);
        const int g1 = 64 * (gray6(2 * i) ^ 1);
        lds[g0 + gtl]        = v[i].x * v[i].x;   // bank = gtl&31: 2-way, free
        lds[g1 + (gtl ^ 32)] = v[i].y * v[i].y;
    }

    float acc[NCLASS];
#pragma unroll
    for (int c = 0; c < NCLASS; ++c) acc[c] = 0.f;

    // R9: unroll 2 -> 20 W-loads in flight per iteration (epilogue is
    // VMEM-latency-bound with only 2 waves/SIMD to hide it)
#pragma unroll 2
    for (int k = 0; k < 16; ++k) {
        const v4f q4 = *(const v4f*)(lds + 4 * t + 256 * k);   // b128, floor-free
        const float* wp = W + 4 * t + 256 * k;
#pragma unroll
        for (int c = 0; c < NCLASS; ++c) {
            const v4f w4 = *(const v4f*)(wp + c * DIM);         // dwordx4, L2-resident
            acc[c] += q4.x * w4.x + q4.y * w4.y + q4.z * w4.z + q4.w * w4.w;
        }
    }

#pragma unroll
    for (int c = 0; c < NCLASS; ++c) {
        float a = acc[c];
#pragma unroll
        for (int o = 1; o < 64; o <<= 1) a += __shfl_xor(a, o, 64);
        if (t == 0) out[b * NCLASS + c] = fmaf(a, invn2, bias[c]);
    }
}

extern "C" void kernel_launch(void* const* d_in, const int* in_sizes, int n_in,
                              void* d_out, int out_size, void* d_ws, size_t ws_size,
                              hipStream_t stream) {
    const float* x    = (const float*)d_in[0];
    const float* ang  = (const float*)d_in[1];
    const float* W    = (const float*)d_in[2];
    const float* bias = (const float*)d_in[3];
    float* out = (float*)d_out;
    const int batch = in_sizes[0] / FEAT;   // 2048
    qnn_kernel<<<batch, 64, 0, stream>>>(x, ang, W, bias, out);
}